// Round 1
// baseline (19913.777 us; speedup 1.0000x reference)
//
#include <hip/hip_runtime.h>
#include <math.h>

#define TB   64     // batch
#define TT   255    // time length
#define TIN  32     // conv1 input channels
#define NH   256    // hidden channels
#define NE   128    // embed channels
#define NK   255    // kernel length
#define NPAD 127

// ---- workspace layout (float offsets) ----
#define OFF_WT1  0u           // [8160][256]  transposed conv1_w
#define OFF_WT2  2088960u     // [65280][128] transposed conv2_w
#define OFF_H    10444800u    // [B][256][255] relu(conv1+b)
#define OFF_Z    14622720u    // [B][128][255] conv2 output (channel-major)
#define OFF_BNSC 16711680u    // [256] bn scale
#define OFF_BNSH 16711936u    // [256] bn shift
#define WS_FLOATS 16712192u   // 66.85 MB total
#define OFF_HMID 0u           // [B][128][256], aliases WT1/WT2 (dead after conv2)

// ---- output layout (float offsets into d_out) ----
#define O_AMP   0u      // (64,127)
#define O_PHASE 8128u   // (64,128)
#define O_FREQ  16320u  // (64,127)
#define O_OFF   24448u  // (64,128)

// ---------------- transpose [R][C] -> [C][R] (dims multiples of 32) -------------
__global__ __launch_bounds__(256) void transpose_k(const float* __restrict__ src,
                                                   float* __restrict__ dst,
                                                   int R, int C) {
  __shared__ float tile[32][33];
  int c0 = blockIdx.x * 32, r0 = blockIdx.y * 32;
  int tx = threadIdx.x & 31, ty = threadIdx.x >> 5;
#pragma unroll
  for (int j = 0; j < 32; j += 8)
    tile[ty + j][tx] = src[(size_t)(r0 + ty + j) * C + c0 + tx];
  __syncthreads();
#pragma unroll
  for (int j = 0; j < 32; j += 8)
    dst[(size_t)(c0 + ty + j) * R + r0 + tx] = tile[tx][ty + j];
}

// ---------------- conv1: h = relu(conv(x,w1)+b1), x from s (B,T,IN) -------------
// grid (8, B): 32 output channels per block, lanes over t, x[b] whole in LDS.
__global__ __launch_bounds__(256) void conv1_k(const float* __restrict__ s,
                                               const float* __restrict__ wt1,
                                               const float* __restrict__ b1,
                                               float* __restrict__ h) {
  __shared__ float xl[TIN * 257];
  const int b = blockIdx.y;
  const int c0 = blockIdx.x * 32;
  const int tid = threadIdx.x;
  for (int idx = tid; idx < TT * TIN; idx += 256) {
    int t = idx >> 5, i = idx & 31;              // s[b][t][i] -> xl[i][t]
    xl[i * 257 + t] = s[(size_t)(b * TT + t) * TIN + i];
  }
  __syncthreads();
  const int lane = tid & 63, wv = tid >> 6;
  const int t = wv * 64 + lane;
  const int tbase = wv * 64;
  const int klo = max(0, NPAD - (tbase + 63));
  const int khi = min(NK - 1, NPAD + (TT - 1) - tbase);
  float acc[32];
#pragma unroll
  for (int j = 0; j < 32; ++j) acc[j] = 0.f;
  for (int i = 0; i < TIN; ++i) {
    const float* xrow = xl + i * 257;
    const float* wrow = wt1 + (size_t)i * NK * NH + c0;
    for (int k = klo; k <= khi; ++k) {
      int tt = t + k - NPAD;
      int ttc = tt < 0 ? 0 : (tt > TT - 1 ? TT - 1 : tt);
      float xv = xrow[ttc];
      xv = (tt == ttc) ? xv : 0.f;
      const float* wp = wrow + (size_t)k * NH;   // wave-uniform -> scalar loads
#pragma unroll
      for (int j = 0; j < 32; ++j) acc[j] = fmaf(xv, wp[j], acc[j]);
    }
  }
  if (t < TT) {
#pragma unroll
    for (int j = 0; j < 32; ++j) {
      float v = acc[j] + b1[c0 + j];
      h[(size_t)(b * NH + c0 + j) * TT + t] = fmaxf(v, 0.f);
    }
  }
}

// ---------------- BN stats: per-channel scale/shift (training-mode, biased) -----
__global__ __launch_bounds__(256) void bn_stats_k(const float* __restrict__ h,
                                                  const float* __restrict__ gamma,
                                                  const float* __restrict__ beta,
                                                  float* __restrict__ bnsc,
                                                  float* __restrict__ bnsh) {
  __shared__ float r1[256], r2[256];
  const int c = blockIdx.x, tid = threadIdx.x;
  float s1 = 0.f, s2 = 0.f;
  for (int idx = tid; idx < TB * TT; idx += 256) {
    int b = idx / TT, t = idx - b * TT;
    float v = h[(size_t)(b * NH + c) * TT + t];
    s1 += v; s2 += v * v;
  }
  r1[tid] = s1; r2[tid] = s2;
  __syncthreads();
  for (int sft = 128; sft; sft >>= 1) {
    if (tid < sft) { r1[tid] += r1[tid + sft]; r2[tid] += r2[tid + sft]; }
    __syncthreads();
  }
  if (tid == 0) {
    const float inv = 1.0f / (TB * TT);
    float m = r1[0] * inv;
    float var = r2[0] * inv - m * m;
    float sc = gamma[c] * rsqrtf(var + 1e-5f);
    bnsc[c] = sc;
    bnsh[c] = beta[c] - m * sc;
  }
}

// ---------------- conv2: z = conv(bn(h), w2) + b2, z stored (B,E,T) -------------
// grid (4, B): 32 e-channels per block; h[b] staged in 16-channel LDS chunks.
__global__ __launch_bounds__(256) void conv2_k(const float* __restrict__ h,
                                               const float* __restrict__ wt2,
                                               const float* __restrict__ bnsc,
                                               const float* __restrict__ bnsh,
                                               const float* __restrict__ b2,
                                               float* __restrict__ z) {
  __shared__ float hl[16 * 257];
  const int b = blockIdx.y;
  const int e0 = blockIdx.x * 32;
  const int tid = threadIdx.x;
  const int lane = tid & 63, wv = tid >> 6;
  const int t = wv * 64 + lane;
  const int tbase = wv * 64;
  const int klo = max(0, NPAD - (tbase + 63));
  const int khi = min(NK - 1, NPAD + (TT - 1) - tbase);
  float acc[32];
#pragma unroll
  for (int j = 0; j < 32; ++j) acc[j] = 0.f;
  for (int ic = 0; ic < 16; ++ic) {
    __syncthreads();
    for (int idx = tid; idx < 16 * TT; idx += 256) {
      int ii = idx / TT, t2 = idx - ii * TT;
      int ch = ic * 16 + ii;
      hl[ii * 257 + t2] = h[(size_t)(b * NH + ch) * TT + t2] * bnsc[ch] + bnsh[ch];
    }
    __syncthreads();
    for (int ii = 0; ii < 16; ++ii) {
      const float* hrow = hl + ii * 257;
      const float* wrow = wt2 + (size_t)(ic * 16 + ii) * NK * NE + e0;
      for (int k = klo; k <= khi; ++k) {
        int tt = t + k - NPAD;
        int ttc = tt < 0 ? 0 : (tt > TT - 1 ? TT - 1 : tt);
        float xv = hrow[ttc];
        xv = (tt == ttc) ? xv : 0.f;
        const float* wp = wrow + (size_t)k * NE;
#pragma unroll
        for (int j = 0; j < 32; ++j) acc[j] = fmaf(xv, wp[j], acc[j]);
      }
    }
  }
  if (t < TT) {
#pragma unroll
    for (int j = 0; j < 32; ++j)
      z[(size_t)(b * NE + e0 + j) * TT + t] = acc[j] + b2[e0 + j];
  }
}

// ---------------- MLP layer 1: hmid[b,c,h] = relu(sum_t z[b,t,c]*pw1[c,h,t]+pb1) -
// grid (4, 128): per block one channel c, 64 h's; tile (4h x 4b) per thread.
__global__ __launch_bounds__(256) void mlp1_k(const float* __restrict__ z,
                                              const float* __restrict__ pw1,
                                              const float* __restrict__ pb1,
                                              float* __restrict__ hmid) {
  const int TC = 128;
  __shared__ float zl[TC * 68];   // [t][b]
  __shared__ float pl[TC * 68];   // [t][h']
  const int c = blockIdx.y, h0 = blockIdx.x * 64, tid = threadIdx.x;
  const int h4 = tid & 15, b4 = tid >> 4;
  float acc[4][4];
#pragma unroll
  for (int a = 0; a < 4; ++a)
#pragma unroll
    for (int bb = 0; bb < 4; ++bb) acc[a][bb] = 0.f;
  for (int t0 = 0; t0 < TT; t0 += TC) {
    const int tc = min(TC, TT - t0);
    __syncthreads();
    for (int idx = tid; idx < 64 * tc; idx += 256) {
      int r = idx / tc, t = idx - r * tc;
      zl[t * 68 + r] = z[(size_t)(r * NE + c) * TT + t0 + t];
      pl[t * 68 + r] = pw1[(size_t)(c * NH + h0 + r) * TT + t0 + t];
    }
    __syncthreads();
    for (int t = 0; t < tc; ++t) {
      float4 zv = *(const float4*)&zl[t * 68 + b4 * 4];
      float4 pv = *(const float4*)&pl[t * 68 + h4 * 4];
      float zz[4] = {zv.x, zv.y, zv.z, zv.w};
      float pp[4] = {pv.x, pv.y, pv.z, pv.w};
#pragma unroll
      for (int a = 0; a < 4; ++a)
#pragma unroll
        for (int bb = 0; bb < 4; ++bb) acc[a][bb] = fmaf(pp[a], zz[bb], acc[a][bb]);
    }
  }
#pragma unroll
  for (int a = 0; a < 4; ++a) {
    int hh = h0 + h4 * 4 + a;
    float bias = pb1[c * NH + hh];
#pragma unroll
    for (int bb = 0; bb < 4; ++bb) {
      int bidx = b4 * 4 + bb;
      float v = acc[a][bb] + bias;
      hmid[(size_t)(bidx * NE + c) * NH + hh] = fmaxf(v, 0.f);
    }
  }
}

// ---------------- MLP layer 2 + atan2: one wave per (b,c) ----------------------
__global__ __launch_bounds__(256) void mlp2_k(const float* __restrict__ hmid,
                                              const float* __restrict__ pw2,
                                              const float* __restrict__ pb2,
                                              float* __restrict__ out) {
  const int tid = threadIdx.x, lane = tid & 63, wv = tid >> 6;
  const int p = blockIdx.x * 4 + wv;      // 0..8191
  const int b = p >> 7, c = p & 127;
  const float4 hv = *(const float4*)&hmid[(size_t)(b * NE + c) * NH + lane * 4];
  const float4 p0 = *(const float4*)&pw2[(size_t)(c * 2 + 0) * NH + lane * 4];
  const float4 p1 = *(const float4*)&pw2[(size_t)(c * 2 + 1) * NH + lane * 4];
  float s0 = hv.x * p0.x + hv.y * p0.y + hv.z * p0.z + hv.w * p0.w;
  float s1 = hv.x * p1.x + hv.y * p1.y + hv.z * p1.z + hv.w * p1.w;
#pragma unroll
  for (int off = 32; off; off >>= 1) {
    s0 += __shfl_down(s0, off);
    s1 += __shfl_down(s1, off);
  }
  if (lane == 0) {
    float a0 = s0 + pb2[c * 2 + 0];
    float a1 = s1 + pb2[c * 2 + 1];
    out[O_PHASE + b * NE + c] = atan2f(a1, a0);
  }
}

// ---------------- amplitude (Parseval) + constant frequency --------------------
__global__ __launch_bounds__(256) void amp_k(const float* __restrict__ z,
                                             float* __restrict__ out) {
  const int tid = threadIdx.x, lane = tid & 63, wv = tid >> 6;
  const int b = blockIdx.x, c = blockIdx.y * 4 + wv;
  const float* row = z + (size_t)(b * NE + c) * TT;
  float s1 = 0.f, s2 = 0.f;
  for (int idx = lane; idx < TT; idx += 64) {
    float v = row[idx];
    s1 += v; s2 += v * v;
  }
#pragma unroll
  for (int off = 32; off; off >>= 1) {
    s1 += __shfl_down(s1, off);
    s2 += __shfl_down(s2, off);
  }
  if (lane == 0 && c >= 1) {
    float P = 0.5f * (255.f * s2 + s1 * s1);   // sum_{f=0..127} |Z_f|^2
    out[O_AMP + b * 127 + (c - 1)] = 2.f * sqrtf(P) / 255.f;
    out[O_FREQ + b * 127 + (c - 1)] = (float)c / 255.f;
  }
}

// ---------------- offset: real rfft spectrum of channel 0 ----------------------
__global__ __launch_bounds__(128) void offset_k(const float* __restrict__ z,
                                                float* __restrict__ out) {
  __shared__ float zr[TT];
  __shared__ float ct[TT];
  const int b = blockIdx.x, tid = threadIdx.x;
  for (int idx = tid; idx < TT; idx += 128) {
    zr[idx] = z[(size_t)(b * NE + 0) * TT + idx];
    ct[idx] = cosf(6.283185307179586f * (float)idx / 255.f);
  }
  __syncthreads();
  const int f = tid;      // 0..127
  float s = 0.f;
  int m = 0;              // (f*t) mod 255, incrementally exact
  for (int t = 0; t < TT; ++t) {
    s += zr[t] * ct[m];
    m += f; if (m >= TT) m -= TT;
  }
  out[O_OFF + b * NE + f] = s / 255.f;
}

extern "C" void kernel_launch(void* const* d_in, const int* in_sizes, int n_in,
                              void* d_out, int out_size, void* d_ws, size_t ws_size,
                              hipStream_t stream) {
  (void)in_sizes; (void)n_in; (void)out_size; (void)ws_size;
  const float* s       = (const float*)d_in[0];
  const float* conv1_w = (const float*)d_in[1];
  const float* conv1_b = (const float*)d_in[2];
  const float* bn_g    = (const float*)d_in[3];
  const float* bn_b    = (const float*)d_in[4];
  const float* conv2_w = (const float*)d_in[5];
  const float* conv2_b = (const float*)d_in[6];
  const float* pw1     = (const float*)d_in[7];
  const float* pb1     = (const float*)d_in[8];
  const float* pw2     = (const float*)d_in[9];
  const float* pb2     = (const float*)d_in[10];
  float* out = (float*)d_out;
  float* ws  = (float*)d_ws;

  float* wt1  = ws + OFF_WT1;
  float* wt2  = ws + OFF_WT2;
  float* h    = ws + OFF_H;
  float* z    = ws + OFF_Z;
  float* bnsc = ws + OFF_BNSC;
  float* bnsh = ws + OFF_BNSH;
  float* hmid = ws + OFF_HMID;   // aliases wt1/wt2, safe after conv2

  // weight transposes: w1 (256 x 8160) -> (8160 x 256); w2 (128 x 65280) -> (65280 x 128)
  transpose_k<<<dim3(255, 8), 256, 0, stream>>>(conv1_w, wt1, NH, TIN * NK);
  transpose_k<<<dim3(2040, 4), 256, 0, stream>>>(conv2_w, wt2, NE, NH * NK);

  conv1_k<<<dim3(8, TB), 256, 0, stream>>>(s, wt1, conv1_b, h);
  bn_stats_k<<<dim3(NH), 256, 0, stream>>>(h, bn_g, bn_b, bnsc, bnsh);
  conv2_k<<<dim3(4, TB), 256, 0, stream>>>(h, wt2, bnsc, bnsh, conv2_b, z);

  mlp1_k<<<dim3(4, NE), 256, 0, stream>>>(z, pw1, pb1, hmid);
  mlp2_k<<<dim3(TB * NE / 4), 256, 0, stream>>>(hmid, pw2, pb2, out);
  amp_k<<<dim3(TB, 32), 256, 0, stream>>>(z, out);
  offset_k<<<dim3(TB), 128, 0, stream>>>(z, out);
}

// Round 3
// 1673.377 us; speedup vs baseline: 11.9004x; 11.9004x over previous
//
#include <hip/hip_runtime.h>
#include <math.h>

#define TB   64
#define TT   255
#define TIN  32
#define NH   256
#define NE   128
#define NK   255
#define NPAD 127

typedef __attribute__((ext_vector_type(8))) short short8;
typedef __attribute__((ext_vector_type(4))) float float4v;

// ---- workspace layout (byte offsets) ----
// wp1: [255][16 et][2 p][64][8] bf16 = 8,355,840 B   (aliased by z after conv1)
// wp2: [255][8 hs][8 et][2 p][64][8] bf16 = 33,423,360 B
// h  : [64][256 t][256 ch] f32 = 16,777,216 B        (aliased by hmid after conv2)
// z  : [64][128 e][255 t] f32 = 8,355,840 B          (aliases wp1)
#define WSB_WP1  0u
#define WSB_Z    0u
#define WSB_WP2  8388608u
#define WSB_H    41811968u
#define WSB_HMID 41811968u
#define WSB_BN   58589184u   // 4 x 256 f32: sum1/sum2/sc/sh

// ---- output layout (float offsets) ----
#define O_AMP   0u
#define O_PHASE 8128u
#define O_FREQ  16320u
#define O_OFF   24448u

static __device__ __forceinline__ unsigned short f2bf(float f) {
  unsigned int u = __float_as_uint(f);
  unsigned int r = (u + 0x7FFFu + ((u >> 16) & 1u)) >> 16;
  return (unsigned short)r;
}
static __device__ __forceinline__ float bf2f(unsigned short s) {
  return __uint_as_float(((unsigned int)s) << 16);
}

#define GLOAD_LDS16(g, l)                                                     \
  __builtin_amdgcn_global_load_lds(                                           \
      (const __attribute__((address_space(1))) unsigned int*)(g),             \
      (__attribute__((address_space(3))) unsigned int*)(l), 16, 0, 0)

// ---------------- small init kernels ----------------
__global__ __launch_bounds__(256) void bn_zero_k(float* __restrict__ bn) {
  bn[threadIdx.x] = 0.f;
  bn[256 + threadIdx.x] = 0.f;
}

__global__ __launch_bounds__(1024) void z_init_k(const float* __restrict__ b2,
                                                 float* __restrict__ z) {
  int idx = blockIdx.x * 1024 + threadIdx.x;   // 2040*1024 == 64*128*255
  int e = (idx / TT) % NE;
  z[idx] = b2[e];
}

// ---------------- weight packing (hi/lo split) ----------------
// wp1[kk][et][p][lane][j]: value = split_p( w1[e=et*16+(lane&15)][i=(lane>>4)*8+j][kk] )
__global__ __launch_bounds__(256) void pack1_k(const float* __restrict__ w1,
                                               unsigned int* __restrict__ wp1u) {
  __shared__ float tile[512][33];
  const int et = blockIdx.x, kc = blockIdx.y;
  const int kk0 = kc * 32, cnt = min(32, NK - kk0);
  const int tid = threadIdx.x;
  for (int idx = tid; idx < 512 * 32; idx += 256) {
    int row = idx >> 5, kl = idx & 31;
    if (kl < cnt) {
      int e_l = row >> 5, i_l = row & 31;
      tile[row][kl] = w1[(size_t)((et * 16 + e_l) * TIN + i_l) * NK + kk0 + kl];
    }
  }
  __syncthreads();
  const int lane = tid >> 2, jp = (tid & 3) * 2;
  const int row0 = (lane & 15) * 32 + (lane >> 4) * 8 + jp;
  for (int kl = 0; kl < cnt; ++kl) {
    float w0 = tile[row0][kl], w1v = tile[row0 + 1][kl];
    unsigned short h0 = f2bf(w0), h1 = f2bf(w1v);
    unsigned short l0 = f2bf(w0 - bf2f(h0)), l1 = f2bf(w1v - bf2f(h1));
    size_t base = (size_t)(kk0 + kl) * 8192 + et * 512 + tid;
    wp1u[base] = (unsigned int)h0 | ((unsigned int)h1 << 16);
    wp1u[base + 256] = (unsigned int)l0 | ((unsigned int)l1 << 16);
  }
}

// wp2[kk][hs][et][p][lane][j]: value = split_p( w2[e=et*16+(lane&15)][h=hs*32+(lane>>4)*8+j][kk] )
__global__ __launch_bounds__(256) void pack2_k(const float* __restrict__ w2,
                                               unsigned int* __restrict__ wp2u) {
  __shared__ float tile[512][33];
  const int hs = blockIdx.x >> 3, et = blockIdx.x & 7, kc = blockIdx.y;
  const int kk0 = kc * 32, cnt = min(32, NK - kk0);
  const int tid = threadIdx.x;
  for (int idx = tid; idx < 512 * 32; idx += 256) {
    int row = idx >> 5, kl = idx & 31;
    if (kl < cnt) {
      int e_l = row >> 5, h_l = row & 31;
      tile[row][kl] = w2[(size_t)((et * 16 + e_l) * NH + hs * 32 + h_l) * NK + kk0 + kl];
    }
  }
  __syncthreads();
  const int lane = tid >> 2, jp = (tid & 3) * 2;
  const int row0 = (lane & 15) * 32 + (lane >> 4) * 8 + jp;
  for (int kl = 0; kl < cnt; ++kl) {
    float w0 = tile[row0][kl], w1v = tile[row0 + 1][kl];
    unsigned short h0 = f2bf(w0), h1 = f2bf(w1v);
    unsigned short l0 = f2bf(w0 - bf2f(h0)), l1 = f2bf(w1v - bf2f(h1));
    size_t base = (size_t)(kk0 + kl) * 32768 + hs * 4096 + et * 512 + tid;
    wp2u[base] = (unsigned int)h0 | ((unsigned int)h1 << 16);
    wp2u[base + 256] = (unsigned int)l0 | ((unsigned int)l1 << 16);
  }
}

// ---------------- conv1 MFMA (split-bf16, 4-term): h fp32 out ----------------
// grid (4 chg, 64 b), 256 thr. Block: 256t x 64ch. Waves: 2tg x 2eg (128t x 32ch).
#define C1_PITCH 72
__global__ __launch_bounds__(256, 1) void conv1_mfma(
    const float* __restrict__ s, const unsigned int* __restrict__ wp1u,
    const float* __restrict__ b1, float* __restrict__ hf) {
  __shared__ __align__(16) unsigned short Alds[512 * C1_PITCH];   // 73,728 B
  __shared__ __align__(16) unsigned short Blds[2][4096];          // 16,384 B
  const int chg = blockIdx.x, b = blockIdx.y;
  const int tid = threadIdx.x, lane = tid & 63, wv = tid >> 6;
  const int quad = lane >> 4, l15 = lane & 15;
  const int tg = wv & 1, eg = wv >> 1;

  for (int i = tid; i < 512 * C1_PITCH / 2; i += 256) ((unsigned int*)Alds)[i] = 0u;
  __syncthreads();
  for (int idx = tid; idx < TT * TIN; idx += 256) {
    int t = idx >> 5, i = idx & 31;
    float v = s[(size_t)(b * TT + t) * TIN + i];
    unsigned short hi = f2bf(v);
    unsigned short lo = f2bf(v - bf2f(hi));
    Alds[(t + NPAD) * C1_PITCH + i] = hi;
    Alds[(t + NPAD) * C1_PITCH + 32 + i] = lo;
  }
  {
    const unsigned int* src = wp1u + (size_t)chg * 2048;
#pragma unroll
    for (int sg = 0; sg < 2; ++sg) {
      int sgi = wv * 2 + sg;
      GLOAD_LDS16(src + sgi * 256 + lane * 4, &Blds[0][sgi * 512]);
    }
  }
  __syncthreads();

  float4v acc[8][2];
#pragma unroll
  for (int mi = 0; mi < 8; ++mi)
#pragma unroll
    for (int ni = 0; ni < 2; ++ni) acc[mi][ni] = (float4v)(0.f);

  int buf = 0;
  for (int kk = 0; kk < NK; ++kk) {
    if (kk + 1 < NK) {
      const unsigned int* src = wp1u + (size_t)(kk + 1) * 8192 + chg * 2048;
#pragma unroll
      for (int sg = 0; sg < 2; ++sg) {
        int sgi = wv * 2 + sg;
        GLOAD_LDS16(src + sgi * 256 + lane * 4, &Blds[buf ^ 1][sgi * 512]);
      }
    }
    short8 ah[8], al[8], bh[2], bl[2];
    const int rowb = tg * 128 + l15 + kk;
#pragma unroll
    for (int mi = 0; mi < 8; ++mi) {
      ah[mi] = *(const short8*)&Alds[(rowb + mi * 16) * C1_PITCH + quad * 8];
      al[mi] = *(const short8*)&Alds[(rowb + mi * 16) * C1_PITCH + 32 + quad * 8];
    }
#pragma unroll
    for (int ni = 0; ni < 2; ++ni) {
      int et = eg * 2 + ni;
      bh[ni] = *(const short8*)&Blds[buf][et * 1024 + lane * 8];
      bl[ni] = *(const short8*)&Blds[buf][et * 1024 + 512 + lane * 8];
    }
#pragma unroll
    for (int mi = 0; mi < 8; ++mi)
#pragma unroll
      for (int ni = 0; ni < 2; ++ni) {
        acc[mi][ni] = __builtin_amdgcn_mfma_f32_16x16x32_bf16(ah[mi], bh[ni], acc[mi][ni], 0, 0, 0);
        acc[mi][ni] = __builtin_amdgcn_mfma_f32_16x16x32_bf16(ah[mi], bl[ni], acc[mi][ni], 0, 0, 0);
        acc[mi][ni] = __builtin_amdgcn_mfma_f32_16x16x32_bf16(al[mi], bh[ni], acc[mi][ni], 0, 0, 0);
        acc[mi][ni] = __builtin_amdgcn_mfma_f32_16x16x32_bf16(al[mi], bl[ni], acc[mi][ni], 0, 0, 0);
      }
    __syncthreads();
    buf ^= 1;
  }

#pragma unroll
  for (int mi = 0; mi < 8; ++mi) {
#pragma unroll
    for (int ni = 0; ni < 2; ++ni) {
      int ch = chg * 64 + eg * 32 + ni * 16 + l15;
      float bias = b1[ch];
#pragma unroll
      for (int r = 0; r < 4; ++r) {
        int t = tg * 128 + mi * 16 + quad * 4 + r;
        if (t < TT)
          hf[(size_t)(b * 256 + t) * NH + ch] = fmaxf(acc[mi][ni][r] + bias, 0.f);
      }
    }
  }
}

// ---------------- BN stats from fp32 h ----------------
__global__ __launch_bounds__(256) void bn_stats_k(const float* __restrict__ hf,
                                                  float* __restrict__ bn) {
  const int b = blockIdx.x, h = threadIdx.x;
  float s1 = 0.f, s2 = 0.f;
  for (int t = 0; t < TT; ++t) {
    float v = hf[(size_t)(b * 256 + t) * NH + h];
    s1 += v; s2 += v * v;
  }
  atomicAdd(&bn[h], s1);
  atomicAdd(&bn[256 + h], s2);
}

__global__ __launch_bounds__(256) void bn_final_k(const float* __restrict__ gamma,
                                                  const float* __restrict__ beta,
                                                  float* __restrict__ bn) {
  const int h = threadIdx.x;
  const float inv = 1.0f / (TB * TT);
  float m = bn[h] * inv;
  float var = bn[256 + h] * inv - m * m;
  float sc = gamma[h] / sqrtf(var + 1e-5f);
  bn[512 + h] = sc;
  bn[768 + h] = beta[h] - m * sc;
}

// ---------------- conv2 MFMA (split-bf16, 4-term), split-K over h (8 blocks) ---
// grid (8 hs, 64 b), 256 thr. Block: 256t x 128e. Waves: 2tg x 2eg (128t x 64e).
#define C2_PITCH 72
__global__ __launch_bounds__(256, 1) void conv2_mfma(
    const float* __restrict__ hf, const unsigned int* __restrict__ wp2u,
    const float* __restrict__ bn, float* __restrict__ z) {
  __shared__ __align__(16) unsigned short Alds[512 * C2_PITCH];   // 73,728 B
  __shared__ __align__(16) unsigned short Blds[2][8192];          // 32,768 B
  const int hs = blockIdx.x, b = blockIdx.y;
  const int tid = threadIdx.x, lane = tid & 63, wv = tid >> 6;
  const int quad = lane >> 4, l15 = lane & 15;
  const int tg = wv & 1, eg = wv >> 1;

  for (int i = tid; i < 512 * C2_PITCH / 2; i += 256) ((unsigned int*)Alds)[i] = 0u;
  __syncthreads();
  for (int idx = tid; idx < TT * 32; idx += 256) {
    int t = idx >> 5, hl = idx & 31;
    int h = hs * 32 + hl;
    float v = hf[(size_t)(b * 256 + t) * NH + h] * bn[512 + h] + bn[768 + h];
    unsigned short hi = f2bf(v);
    unsigned short lo = f2bf(v - bf2f(hi));
    Alds[(t + NPAD) * C2_PITCH + hl] = hi;
    Alds[(t + NPAD) * C2_PITCH + 32 + hl] = lo;
  }
  {
    const unsigned int* src = wp2u + (size_t)hs * 4096;
#pragma unroll
    for (int sg = 0; sg < 4; ++sg) {
      int sgi = wv * 4 + sg;
      GLOAD_LDS16(src + sgi * 256 + lane * 4, &Blds[0][sgi * 512]);
    }
  }
  __syncthreads();

  float4v acc[8][4];
#pragma unroll
  for (int mi = 0; mi < 8; ++mi)
#pragma unroll
    for (int ni = 0; ni < 4; ++ni) acc[mi][ni] = (float4v)(0.f);

  int buf = 0;
  for (int kk = 0; kk < NK; ++kk) {
    if (kk + 1 < NK) {
      const unsigned int* src = wp2u + (size_t)(kk + 1) * 32768 + hs * 4096;
#pragma unroll
      for (int sg = 0; sg < 4; ++sg) {
        int sgi = wv * 4 + sg;
        GLOAD_LDS16(src + sgi * 256 + lane * 4, &Blds[buf ^ 1][sgi * 512]);
      }
    }
    short8 ah[8], al[8], bh[4], bl[4];
    const int rowb = tg * 128 + l15 + kk;
#pragma unroll
    for (int mi = 0; mi < 8; ++mi) {
      ah[mi] = *(const short8*)&Alds[(rowb + mi * 16) * C2_PITCH + quad * 8];
      al[mi] = *(const short8*)&Alds[(rowb + mi * 16) * C2_PITCH + 32 + quad * 8];
    }
#pragma unroll
    for (int ni = 0; ni < 4; ++ni) {
      int et = eg * 4 + ni;
      bh[ni] = *(const short8*)&Blds[buf][et * 1024 + lane * 8];
      bl[ni] = *(const short8*)&Blds[buf][et * 1024 + 512 + lane * 8];
    }
#pragma unroll
    for (int mi = 0; mi < 8; ++mi)
#pragma unroll
      for (int ni = 0; ni < 4; ++ni) {
        acc[mi][ni] = __builtin_amdgcn_mfma_f32_16x16x32_bf16(ah[mi], bh[ni], acc[mi][ni], 0, 0, 0);
        acc[mi][ni] = __builtin_amdgcn_mfma_f32_16x16x32_bf16(ah[mi], bl[ni], acc[mi][ni], 0, 0, 0);
        acc[mi][ni] = __builtin_amdgcn_mfma_f32_16x16x32_bf16(al[mi], bh[ni], acc[mi][ni], 0, 0, 0);
        acc[mi][ni] = __builtin_amdgcn_mfma_f32_16x16x32_bf16(al[mi], bl[ni], acc[mi][ni], 0, 0, 0);
      }
    __syncthreads();
    buf ^= 1;
  }

#pragma unroll
  for (int mi = 0; mi < 8; ++mi) {
#pragma unroll
    for (int ni = 0; ni < 4; ++ni) {
      int e = eg * 64 + ni * 16 + l15;
#pragma unroll
      for (int r = 0; r < 4; ++r) {
        int t = tg * 128 + mi * 16 + quad * 4 + r;
        if (t < TT) atomicAdd(&z[(size_t)(b * NE + e) * TT + t], acc[mi][ni][r]);
      }
    }
  }
}

// ---------------- MLP layer 1 (fp32) ----------------
__global__ __launch_bounds__(256) void mlp1_k(const float* __restrict__ z,
                                              const float* __restrict__ pw1,
                                              const float* __restrict__ pb1,
                                              float* __restrict__ hmid) {
  const int TC = 128;
  __shared__ float zl[TC * 68];
  __shared__ float pl[TC * 68];
  const int c = blockIdx.y, h0 = blockIdx.x * 64, tid = threadIdx.x;
  const int h4 = tid & 15, b4 = tid >> 4;
  float acc[4][4];
#pragma unroll
  for (int a = 0; a < 4; ++a)
#pragma unroll
    for (int bb = 0; bb < 4; ++bb) acc[a][bb] = 0.f;
  for (int t0 = 0; t0 < TT; t0 += TC) {
    const int tc = min(TC, TT - t0);
    __syncthreads();
    for (int idx = tid; idx < 64 * tc; idx += 256) {
      int r = idx / tc, t = idx - r * tc;
      zl[t * 68 + r] = z[(size_t)(r * NE + c) * TT + t0 + t];
      pl[t * 68 + r] = pw1[(size_t)(c * NH + h0 + r) * TT + t0 + t];
    }
    __syncthreads();
    for (int t = 0; t < tc; ++t) {
      float4 zv = *(const float4*)&zl[t * 68 + b4 * 4];
      float4 pv = *(const float4*)&pl[t * 68 + h4 * 4];
      float zz[4] = {zv.x, zv.y, zv.z, zv.w};
      float pp[4] = {pv.x, pv.y, pv.z, pv.w};
#pragma unroll
      for (int a = 0; a < 4; ++a)
#pragma unroll
        for (int bb = 0; bb < 4; ++bb) acc[a][bb] = fmaf(pp[a], zz[bb], acc[a][bb]);
    }
  }
#pragma unroll
  for (int a = 0; a < 4; ++a) {
    int hh = h0 + h4 * 4 + a;
    float bias = pb1[c * NH + hh];
#pragma unroll
    for (int bb = 0; bb < 4; ++bb) {
      int bidx = b4 * 4 + bb;
      float v = acc[a][bb] + bias;
      hmid[(size_t)(bidx * NE + c) * NH + hh] = fmaxf(v, 0.f);
    }
  }
}

// ---------------- MLP layer 2 + atan2 ----------------
__global__ __launch_bounds__(256) void mlp2_k(const float* __restrict__ hmid,
                                              const float* __restrict__ pw2,
                                              const float* __restrict__ pb2,
                                              float* __restrict__ out) {
  const int tid = threadIdx.x, lane = tid & 63, wv = tid >> 6;
  const int p = blockIdx.x * 4 + wv;
  const int b = p >> 7, c = p & 127;
  const float4 hv = *(const float4*)&hmid[(size_t)(b * NE + c) * NH + lane * 4];
  const float4 p0 = *(const float4*)&pw2[(size_t)(c * 2 + 0) * NH + lane * 4];
  const float4 p1 = *(const float4*)&pw2[(size_t)(c * 2 + 1) * NH + lane * 4];
  float s0 = hv.x * p0.x + hv.y * p0.y + hv.z * p0.z + hv.w * p0.w;
  float s1 = hv.x * p1.x + hv.y * p1.y + hv.z * p1.z + hv.w * p1.w;
#pragma unroll
  for (int off = 32; off; off >>= 1) {
    s0 += __shfl_down(s0, off);
    s1 += __shfl_down(s1, off);
  }
  if (lane == 0) {
    float a0 = s0 + pb2[c * 2 + 0];
    float a1 = s1 + pb2[c * 2 + 1];
    out[O_PHASE + b * NE + c] = atan2f(a1, a0);
  }
}

// ---------------- amplitude (Parseval) + constant frequency ----------------
__global__ __launch_bounds__(256) void amp_k(const float* __restrict__ z,
                                             float* __restrict__ out) {
  const int tid = threadIdx.x, lane = tid & 63, wv = tid >> 6;
  const int b = blockIdx.x, c = blockIdx.y * 4 + wv;
  const float* row = z + (size_t)(b * NE + c) * TT;
  float s1 = 0.f, s2 = 0.f;
  for (int idx = lane; idx < TT; idx += 64) {
    float v = row[idx];
    s1 += v; s2 += v * v;
  }
#pragma unroll
  for (int off = 32; off; off >>= 1) {
    s1 += __shfl_down(s1, off);
    s2 += __shfl_down(s2, off);
  }
  if (lane == 0 && c >= 1) {
    float P = 0.5f * (255.f * s2 + s1 * s1);
    out[O_AMP + b * 127 + (c - 1)] = 2.f * sqrtf(P) / 255.f;
    out[O_FREQ + b * 127 + (c - 1)] = (float)c / 255.f;
  }
}

// ---------------- offset: real rfft spectrum of channel 0 ----------------
__global__ __launch_bounds__(128) void offset_k(const float* __restrict__ z,
                                                float* __restrict__ out) {
  __shared__ float zr[TT];
  __shared__ float ct[TT];
  const int b = blockIdx.x, tid = threadIdx.x;
  for (int idx = tid; idx < TT; idx += 128) {
    zr[idx] = z[(size_t)(b * NE + 0) * TT + idx];
    ct[idx] = cosf(6.283185307179586f * (float)idx / 255.f);
  }
  __syncthreads();
  const int f = tid;
  float s = 0.f;
  int m = 0;
  for (int t = 0; t < TT; ++t) {
    s += zr[t] * ct[m];
    m += f; if (m >= TT) m -= TT;
  }
  out[O_OFF + b * NE + f] = s / 255.f;
}

extern "C" void kernel_launch(void* const* d_in, const int* in_sizes, int n_in,
                              void* d_out, int out_size, void* d_ws, size_t ws_size,
                              hipStream_t stream) {
  (void)in_sizes; (void)n_in; (void)out_size; (void)ws_size;
  const float* s       = (const float*)d_in[0];
  const float* conv1_w = (const float*)d_in[1];
  const float* conv1_b = (const float*)d_in[2];
  const float* bn_g    = (const float*)d_in[3];
  const float* bn_b    = (const float*)d_in[4];
  const float* conv2_w = (const float*)d_in[5];
  const float* conv2_b = (const float*)d_in[6];
  const float* pw1     = (const float*)d_in[7];
  const float* pb1     = (const float*)d_in[8];
  const float* pw2     = (const float*)d_in[9];
  const float* pb2     = (const float*)d_in[10];
  float* out = (float*)d_out;
  char* ws   = (char*)d_ws;

  unsigned int* wp1u = (unsigned int*)(ws + WSB_WP1);
  unsigned int* wp2u = (unsigned int*)(ws + WSB_WP2);
  float* hf   = (float*)(ws + WSB_H);
  float* z    = (float*)(ws + WSB_Z);      // aliases wp1 (dead after conv1)
  float* bn   = (float*)(ws + WSB_BN);
  float* hmid = (float*)(ws + WSB_HMID);   // aliases hf (dead after conv2)

  bn_zero_k<<<1, 256, 0, stream>>>(bn);
  pack1_k<<<dim3(16, 8), 256, 0, stream>>>(conv1_w, wp1u);
  pack2_k<<<dim3(64, 8), 256, 0, stream>>>(conv2_w, wp2u);

  conv1_mfma<<<dim3(4, TB), 256, 0, stream>>>(s, wp1u, conv1_b, hf);
  bn_stats_k<<<TB, 256, 0, stream>>>(hf, bn);
  bn_final_k<<<1, 256, 0, stream>>>(bn_g, bn_b, bn);

  z_init_k<<<2040, 1024, 0, stream>>>(conv2_b, z);   // overwrites wp1 region
  conv2_mfma<<<dim3(8, TB), 256, 0, stream>>>(hf, wp2u, bn, z);

  mlp1_k<<<dim3(4, NE), 256, 0, stream>>>(z, pw1, pb1, hmid);
  mlp2_k<<<TB * NE / 4, 256, 0, stream>>>(hmid, pw2, pb2, out);
  amp_k<<<dim3(TB, 32), 256, 0, stream>>>(z, out);
  offset_k<<<TB, 128, 0, stream>>>(z, out);
}

// Round 4
// 1081.408 us; speedup vs baseline: 18.4147x; 1.5474x over previous
//
#include <hip/hip_runtime.h>
#include <math.h>

#define TB   64
#define TT   255
#define TIN  32
#define NH   256
#define NE   128
#define NK   255
#define NPAD 127

typedef __attribute__((ext_vector_type(8))) short short8;
typedef __attribute__((ext_vector_type(4))) float float4v;

// ---- workspace layout (byte offsets) ----
// wp1: [255][16 et][2 p][64][8] bf16 = 8,355,840 B   (aliased by z after conv1)
// wp2: [255][8 hcg][8 et][2 p][64][8] bf16 = 33,423,360 B
// h  : [64][256 t][256 ch] f32 = 16,777,216 B        (aliased by hmid after conv2)
// z  : [64][128 e][255 t] f32 = 8,355,840 B          (aliases wp1)
#define WSB_WP1  0u
#define WSB_Z    0u
#define WSB_WP2  8388608u
#define WSB_H    41811968u
#define WSB_HMID 41811968u
#define WSB_BN   58589184u   // 4 x 256 f32: sum1/sum2/sc/sh

// ---- output layout (float offsets) ----
#define O_AMP   0u
#define O_PHASE 8128u
#define O_FREQ  16320u
#define O_OFF   24448u

static __device__ __forceinline__ unsigned short f2bf(float f) {
  unsigned int u = __float_as_uint(f);
  unsigned int r = (u + 0x7FFFu + ((u >> 16) & 1u)) >> 16;
  return (unsigned short)r;
}
static __device__ __forceinline__ float bf2f(unsigned short s) {
  return __uint_as_float(((unsigned int)s) << 16);
}

#define GLOAD_LDS16(g, l)                                                     \
  __builtin_amdgcn_global_load_lds(                                           \
      (const __attribute__((address_space(1))) unsigned int*)(g),             \
      (__attribute__((address_space(3))) unsigned int*)(l), 16, 0, 0)

// ---------------- small init kernels ----------------
__global__ __launch_bounds__(256) void bn_zero_k(float* __restrict__ bn) {
  bn[threadIdx.x] = 0.f;
  bn[256 + threadIdx.x] = 0.f;
}

__global__ __launch_bounds__(1024) void z_init_k(const float* __restrict__ b2,
                                                 float* __restrict__ z) {
  int idx = blockIdx.x * 1024 + threadIdx.x;   // 2040*1024 == 64*128*255
  int e = (idx / TT) % NE;
  z[idx] = b2[e];
}

// ---------------- weight packing (hi/lo split) ----------------
// wp1[kk][et][p][lane][j]: value = split_p( w1[e=et*16+(lane&15)][i=(lane>>4)*8+j][kk] )
__global__ __launch_bounds__(256) void pack1_k(const float* __restrict__ w1,
                                               unsigned int* __restrict__ wp1u) {
  __shared__ float tile[512][33];
  const int et = blockIdx.x, kc = blockIdx.y;
  const int kk0 = kc * 32, cnt = min(32, NK - kk0);
  const int tid = threadIdx.x;
  for (int idx = tid; idx < 512 * 32; idx += 256) {
    int row = idx >> 5, kl = idx & 31;
    if (kl < cnt) {
      int e_l = row >> 5, i_l = row & 31;
      tile[row][kl] = w1[(size_t)((et * 16 + e_l) * TIN + i_l) * NK + kk0 + kl];
    }
  }
  __syncthreads();
  const int lane = tid >> 2, jp = (tid & 3) * 2;
  const int row0 = (lane & 15) * 32 + (lane >> 4) * 8 + jp;
  for (int kl = 0; kl < cnt; ++kl) {
    float w0 = tile[row0][kl], w1v = tile[row0 + 1][kl];
    unsigned short h0 = f2bf(w0), h1 = f2bf(w1v);
    unsigned short l0 = f2bf(w0 - bf2f(h0)), l1 = f2bf(w1v - bf2f(h1));
    size_t base = (size_t)(kk0 + kl) * 8192 + et * 512 + tid;
    wp1u[base] = (unsigned int)h0 | ((unsigned int)h1 << 16);
    wp1u[base + 256] = (unsigned int)l0 | ((unsigned int)l1 << 16);
  }
}

// wp2[kk][hcg][et][p][lane][j]: value = split_p( w2[e=et*16+(lane&15)][h=hcg*32+(lane>>4)*8+j][kk] )
__global__ __launch_bounds__(256) void pack2_k(const float* __restrict__ w2,
                                               unsigned int* __restrict__ wp2u) {
  __shared__ float tile[512][33];
  const int hcg = blockIdx.x >> 3, et = blockIdx.x & 7, kc = blockIdx.y;
  const int kk0 = kc * 32, cnt = min(32, NK - kk0);
  const int tid = threadIdx.x;
  for (int idx = tid; idx < 512 * 32; idx += 256) {
    int row = idx >> 5, kl = idx & 31;
    if (kl < cnt) {
      int e_l = row >> 5, h_l = row & 31;
      tile[row][kl] = w2[(size_t)((et * 16 + e_l) * NH + hcg * 32 + h_l) * NK + kk0 + kl];
    }
  }
  __syncthreads();
  const int lane = tid >> 2, jp = (tid & 3) * 2;
  const int row0 = (lane & 15) * 32 + (lane >> 4) * 8 + jp;
  for (int kl = 0; kl < cnt; ++kl) {
    float w0 = tile[row0][kl], w1v = tile[row0 + 1][kl];
    unsigned short h0 = f2bf(w0), h1 = f2bf(w1v);
    unsigned short l0 = f2bf(w0 - bf2f(h0)), l1 = f2bf(w1v - bf2f(h1));
    size_t base = (size_t)(kk0 + kl) * 32768 + hcg * 4096 + et * 512 + tid;
    wp2u[base] = (unsigned int)h0 | ((unsigned int)h1 << 16);
    wp2u[base + 256] = (unsigned int)l0 | ((unsigned int)l1 << 16);
  }
}

// ---------------- conv1 MFMA (split-bf16, 3-term), t-split -------------------
// grid (8 = 2 th x 4 chg, 64 b), 256 thr. Block: 128t x 64ch.
// Waves: 2tg x 2eg, each 64t x 32ch (mi=4, ni=2). LDS 64 KB -> 2 blocks/CU.
// A: 384 rows x 64 halves (32 i hi + 32 i lo), 128 B pitch, XOR-swizzled 16B blocks.
#define C1_ROWS 384
__global__ __launch_bounds__(256, 2) void conv1_mfma(
    const float* __restrict__ s, const unsigned int* __restrict__ wp1u,
    const float* __restrict__ b1, float* __restrict__ hf) {
  __shared__ __align__(16) unsigned short Alds[C1_ROWS * 64];   // 49152 B
  __shared__ __align__(16) unsigned short Blds[2][4096];        // 16384 B
  const int th = blockIdx.x & 1, chg = blockIdx.x >> 1, b = blockIdx.y;
  const int tid = threadIdx.x, lane = tid & 63, wv = tid >> 6;
  const int quad = lane >> 4, l15 = lane & 15;
  const int tg = wv & 1, eg = wv >> 1;

  unsigned int* Au = (unsigned int*)Alds;
  for (int idx = tid; idx < C1_ROWS * 16; idx += 256) {
    int r = idx >> 4, p = idx & 15;
    int t = th * 128 + r - NPAD;
    float v0 = 0.f, v1 = 0.f;
    if (t >= 0 && t < TT) {
      const float* sp = &s[(size_t)(b * TT + t) * TIN + p * 2];
      v0 = sp[0]; v1 = sp[1];
    }
    unsigned short h0 = f2bf(v0), h1 = f2bf(v1);
    unsigned short l0 = f2bf(v0 - bf2f(h0)), l1 = f2bf(v1 - bf2f(h1));
    int sw = r & 7;
    Au[r * 32 + ((((p >> 2) ^ sw) << 2) | (p & 3))] = (unsigned int)h0 | ((unsigned int)h1 << 16);
    Au[r * 32 + (((((p >> 2) + 4) ^ sw) << 2) | (p & 3))] = (unsigned int)l0 | ((unsigned int)l1 << 16);
  }
  {
    const unsigned int* src = wp1u + (size_t)chg * 2048;
#pragma unroll
    for (int sg = 0; sg < 2; ++sg) {
      int sgi = wv * 2 + sg;
      GLOAD_LDS16(src + sgi * 256 + lane * 4, &Blds[0][sgi * 512]);
    }
  }
  __syncthreads();

  float4v acc[4][2];
#pragma unroll
  for (int mi = 0; mi < 4; ++mi)
#pragma unroll
    for (int ni = 0; ni < 2; ++ni) acc[mi][ni] = (float4v)(0.f);

  int buf = 0;
  for (int kk = 0; kk < NK; ++kk) {
    if (kk + 1 < NK) {
      const unsigned int* src = wp1u + (size_t)(kk + 1) * 8192 + chg * 2048;
#pragma unroll
      for (int sg = 0; sg < 2; ++sg) {
        int sgi = wv * 2 + sg;
        GLOAD_LDS16(src + sgi * 256 + lane * 4, &Blds[buf ^ 1][sgi * 512]);
      }
    }
    short8 ah[4], al[4], bh[2], bl[2];
#pragma unroll
    for (int mi = 0; mi < 4; ++mi) {
      int row = tg * 64 + mi * 16 + l15 + kk;
      int sw = row & 7;
      ah[mi] = *(const short8*)&Alds[row * 64 + ((quad ^ sw) << 3)];
      al[mi] = *(const short8*)&Alds[row * 64 + ((quad ^ 4 ^ sw) << 3)];
    }
#pragma unroll
    for (int ni = 0; ni < 2; ++ni) {
      int et = eg * 2 + ni;
      bh[ni] = *(const short8*)&Blds[buf][et * 1024 + lane * 8];
      bl[ni] = *(const short8*)&Blds[buf][et * 1024 + 512 + lane * 8];
    }
#pragma unroll
    for (int mi = 0; mi < 4; ++mi)
#pragma unroll
      for (int ni = 0; ni < 2; ++ni) {
        acc[mi][ni] = __builtin_amdgcn_mfma_f32_16x16x32_bf16(ah[mi], bh[ni], acc[mi][ni], 0, 0, 0);
        acc[mi][ni] = __builtin_amdgcn_mfma_f32_16x16x32_bf16(ah[mi], bl[ni], acc[mi][ni], 0, 0, 0);
        acc[mi][ni] = __builtin_amdgcn_mfma_f32_16x16x32_bf16(al[mi], bh[ni], acc[mi][ni], 0, 0, 0);
      }
    __syncthreads();
    buf ^= 1;
  }

#pragma unroll
  for (int mi = 0; mi < 4; ++mi) {
#pragma unroll
    for (int ni = 0; ni < 2; ++ni) {
      int ch = chg * 64 + eg * 32 + ni * 16 + l15;
      float bias = b1[ch];
#pragma unroll
      for (int r = 0; r < 4; ++r) {
        int t = th * 128 + tg * 64 + mi * 16 + quad * 4 + r;
        if (t < TT)
          hf[(size_t)(b * 256 + t) * NH + ch] = fmaxf(acc[mi][ni][r] + bias, 0.f);
      }
    }
  }
}

// ---------------- BN stats from fp32 h ----------------
__global__ __launch_bounds__(256) void bn_stats_k(const float* __restrict__ hf,
                                                  float* __restrict__ bn) {
  const int b = blockIdx.x, h = threadIdx.x;
  float s1 = 0.f, s2 = 0.f;
  for (int t = 0; t < TT; ++t) {
    float v = hf[(size_t)(b * 256 + t) * NH + h];
    s1 += v; s2 += v * v;
  }
  atomicAdd(&bn[h], s1);
  atomicAdd(&bn[256 + h], s2);
}

__global__ __launch_bounds__(256) void bn_final_k(const float* __restrict__ gamma,
                                                  const float* __restrict__ beta,
                                                  float* __restrict__ bn) {
  const int h = threadIdx.x;
  const float inv = 1.0f / (TB * TT);
  float m = bn[h] * inv;
  float var = bn[256 + h] * inv - m * m;
  float sc = gamma[h] / sqrtf(var + 1e-5f);
  bn[512 + h] = sc;
  bn[768 + h] = beta[h] - m * sc;
}

// ---------------- conv2 MFMA (split-bf16, 3-term), t-split + h-chunk loop -----
// grid (8 = 2 th x 4 hs, 64 b), 256 thr. Block: 128t x 128e, 2 h-chunks of 32.
// Waves: 2tg x 2eg, each 64t x 64e (mi=4, ni=4). LDS 80 KB -> 2 blocks/CU.
#define C2_ROWS 384
__global__ __launch_bounds__(256, 2) void conv2_mfma(
    const float* __restrict__ hf, const unsigned int* __restrict__ wp2u,
    const float* __restrict__ bn, float* __restrict__ z) {
  __shared__ __align__(16) unsigned short Alds[C2_ROWS * 64];   // 49152 B
  __shared__ __align__(16) unsigned short Blds[2][8192];        // 32768 B
  const int th = blockIdx.x & 1, hs = blockIdx.x >> 1, b = blockIdx.y;
  const int tid = threadIdx.x, lane = tid & 63, wv = tid >> 6;
  const int quad = lane >> 4, l15 = lane & 15;
  const int tg = wv & 1, eg = wv >> 1;
  unsigned int* Au = (unsigned int*)Alds;

  float4v acc[4][4];
#pragma unroll
  for (int mi = 0; mi < 4; ++mi)
#pragma unroll
    for (int ni = 0; ni < 4; ++ni) acc[mi][ni] = (float4v)(0.f);

  int buf = 0;
  for (int hc = 0; hc < 2; ++hc) {
    const int hcg = hs * 2 + hc;
    __syncthreads();   // protect Alds from overwrite (prior reads done)
    for (int idx = tid; idx < C2_ROWS * 16; idx += 256) {
      int r = idx >> 4, p = idx & 15;
      int t = th * 128 + r - NPAD;
      float v0 = 0.f, v1 = 0.f;
      int h0c = hcg * 32 + p * 2;
      if (t >= 0 && t < TT) {
        const float* hp = &hf[(size_t)(b * 256 + t) * NH + h0c];
        v0 = hp[0] * bn[512 + h0c] + bn[768 + h0c];
        v1 = hp[1] * bn[512 + h0c + 1] + bn[768 + h0c + 1];
      }
      unsigned short h0 = f2bf(v0), h1 = f2bf(v1);
      unsigned short l0 = f2bf(v0 - bf2f(h0)), l1 = f2bf(v1 - bf2f(h1));
      int sw = r & 7;
      Au[r * 32 + ((((p >> 2) ^ sw) << 2) | (p & 3))] = (unsigned int)h0 | ((unsigned int)h1 << 16);
      Au[r * 32 + (((((p >> 2) + 4) ^ sw) << 2) | (p & 3))] = (unsigned int)l0 | ((unsigned int)l1 << 16);
    }
    if (hc == 0) {
      const unsigned int* src = wp2u + (size_t)hcg * 4096;
#pragma unroll
      for (int sg = 0; sg < 4; ++sg) {
        int sgi = wv * 4 + sg;
        GLOAD_LDS16(src + sgi * 256 + lane * 4, &Blds[0][sgi * 512]);
      }
      buf = 0;
    }
    __syncthreads();

    for (int kk = 0; kk < NK; ++kk) {
      int nk = kk + 1, ng = hcg;
      bool pf = true;
      if (nk == NK) { if (hc == 0) { nk = 0; ng = hcg + 1; } else pf = false; }
      if (pf) {
        const unsigned int* src = wp2u + (size_t)nk * 32768 + ng * 4096;
#pragma unroll
        for (int sg = 0; sg < 4; ++sg) {
          int sgi = wv * 4 + sg;
          GLOAD_LDS16(src + sgi * 256 + lane * 4, &Blds[buf ^ 1][sgi * 512]);
        }
      }
      short8 ah[4], al[4], bh[4], bl[4];
#pragma unroll
      for (int mi = 0; mi < 4; ++mi) {
        int row = tg * 64 + mi * 16 + l15 + kk;
        int sw = row & 7;
        ah[mi] = *(const short8*)&Alds[row * 64 + ((quad ^ sw) << 3)];
        al[mi] = *(const short8*)&Alds[row * 64 + ((quad ^ 4 ^ sw) << 3)];
      }
#pragma unroll
      for (int ni = 0; ni < 4; ++ni) {
        int et = eg * 4 + ni;
        bh[ni] = *(const short8*)&Blds[buf][et * 1024 + lane * 8];
        bl[ni] = *(const short8*)&Blds[buf][et * 1024 + 512 + lane * 8];
      }
#pragma unroll
      for (int mi = 0; mi < 4; ++mi)
#pragma unroll
        for (int ni = 0; ni < 4; ++ni) {
          acc[mi][ni] = __builtin_amdgcn_mfma_f32_16x16x32_bf16(ah[mi], bh[ni], acc[mi][ni], 0, 0, 0);
          acc[mi][ni] = __builtin_amdgcn_mfma_f32_16x16x32_bf16(ah[mi], bl[ni], acc[mi][ni], 0, 0, 0);
          acc[mi][ni] = __builtin_amdgcn_mfma_f32_16x16x32_bf16(al[mi], bh[ni], acc[mi][ni], 0, 0, 0);
        }
      __syncthreads();
      buf ^= 1;
    }
  }

#pragma unroll
  for (int mi = 0; mi < 4; ++mi) {
#pragma unroll
    for (int ni = 0; ni < 4; ++ni) {
      int e = eg * 64 + ni * 16 + l15;
#pragma unroll
      for (int r = 0; r < 4; ++r) {
        int t = th * 128 + tg * 64 + mi * 16 + quad * 4 + r;
        if (t < TT) atomicAdd(&z[(size_t)(b * NE + e) * TT + t], acc[mi][ni][r]);
      }
    }
  }
}

// ---------------- MLP layer 1 (fp32) ----------------
__global__ __launch_bounds__(256) void mlp1_k(const float* __restrict__ z,
                                              const float* __restrict__ pw1,
                                              const float* __restrict__ pb1,
                                              float* __restrict__ hmid) {
  const int TC = 128;
  __shared__ float zl[TC * 68];
  __shared__ float pl[TC * 68];
  const int c = blockIdx.y, h0 = blockIdx.x * 64, tid = threadIdx.x;
  const int h4 = tid & 15, b4 = tid >> 4;
  float acc[4][4];
#pragma unroll
  for (int a = 0; a < 4; ++a)
#pragma unroll
    for (int bb = 0; bb < 4; ++bb) acc[a][bb] = 0.f;
  for (int t0 = 0; t0 < TT; t0 += TC) {
    const int tc = min(TC, TT - t0);
    __syncthreads();
    for (int idx = tid; idx < 64 * tc; idx += 256) {
      int r = idx / tc, t = idx - r * tc;
      zl[t * 68 + r] = z[(size_t)(r * NE + c) * TT + t0 + t];
      pl[t * 68 + r] = pw1[(size_t)(c * NH + h0 + r) * TT + t0 + t];
    }
    __syncthreads();
    for (int t = 0; t < tc; ++t) {
      float4 zv = *(const float4*)&zl[t * 68 + b4 * 4];
      float4 pv = *(const float4*)&pl[t * 68 + h4 * 4];
      float zz[4] = {zv.x, zv.y, zv.z, zv.w};
      float pp[4] = {pv.x, pv.y, pv.z, pv.w};
#pragma unroll
      for (int a = 0; a < 4; ++a)
#pragma unroll
        for (int bb = 0; bb < 4; ++bb) acc[a][bb] = fmaf(pp[a], zz[bb], acc[a][bb]);
    }
  }
#pragma unroll
  for (int a = 0; a < 4; ++a) {
    int hh = h0 + h4 * 4 + a;
    float bias = pb1[c * NH + hh];
#pragma unroll
    for (int bb = 0; bb < 4; ++bb) {
      int bidx = b4 * 4 + bb;
      float v = acc[a][bb] + bias;
      hmid[(size_t)(bidx * NE + c) * NH + hh] = fmaxf(v, 0.f);
    }
  }
}

// ---------------- MLP layer 2 + atan2 ----------------
__global__ __launch_bounds__(256) void mlp2_k(const float* __restrict__ hmid,
                                              const float* __restrict__ pw2,
                                              const float* __restrict__ pb2,
                                              float* __restrict__ out) {
  const int tid = threadIdx.x, lane = tid & 63, wv = tid >> 6;
  const int p = blockIdx.x * 4 + wv;
  const int b = p >> 7, c = p & 127;
  const float4 hv = *(const float4*)&hmid[(size_t)(b * NE + c) * NH + lane * 4];
  const float4 p0 = *(const float4*)&pw2[(size_t)(c * 2 + 0) * NH + lane * 4];
  const float4 p1 = *(const float4*)&pw2[(size_t)(c * 2 + 1) * NH + lane * 4];
  float s0 = hv.x * p0.x + hv.y * p0.y + hv.z * p0.z + hv.w * p0.w;
  float s1 = hv.x * p1.x + hv.y * p1.y + hv.z * p1.z + hv.w * p1.w;
#pragma unroll
  for (int off = 32; off; off >>= 1) {
    s0 += __shfl_down(s0, off);
    s1 += __shfl_down(s1, off);
  }
  if (lane == 0) {
    float a0 = s0 + pb2[c * 2 + 0];
    float a1 = s1 + pb2[c * 2 + 1];
    out[O_PHASE + b * NE + c] = atan2f(a1, a0);
  }
}

// ---------------- amplitude (Parseval) + constant frequency ----------------
__global__ __launch_bounds__(256) void amp_k(const float* __restrict__ z,
                                             float* __restrict__ out) {
  const int tid = threadIdx.x, lane = tid & 63, wv = tid >> 6;
  const int b = blockIdx.x, c = blockIdx.y * 4 + wv;
  const float* row = z + (size_t)(b * NE + c) * TT;
  float s1 = 0.f, s2 = 0.f;
  for (int idx = lane; idx < TT; idx += 64) {
    float v = row[idx];
    s1 += v; s2 += v * v;
  }
#pragma unroll
  for (int off = 32; off; off >>= 1) {
    s1 += __shfl_down(s1, off);
    s2 += __shfl_down(s2, off);
  }
  if (lane == 0 && c >= 1) {
    float P = 0.5f * (255.f * s2 + s1 * s1);
    out[O_AMP + b * 127 + (c - 1)] = 2.f * sqrtf(P) / 255.f;
    out[O_FREQ + b * 127 + (c - 1)] = (float)c / 255.f;
  }
}

// ---------------- offset: real rfft spectrum of channel 0 ----------------
__global__ __launch_bounds__(128) void offset_k(const float* __restrict__ z,
                                                float* __restrict__ out) {
  __shared__ float zr[TT];
  __shared__ float ct[TT];
  const int b = blockIdx.x, tid = threadIdx.x;
  for (int idx = tid; idx < TT; idx += 128) {
    zr[idx] = z[(size_t)(b * NE + 0) * TT + idx];
    ct[idx] = cosf(6.283185307179586f * (float)idx / 255.f);
  }
  __syncthreads();
  const int f = tid;
  float s = 0.f;
  int m = 0;
  for (int t = 0; t < TT; ++t) {
    s += zr[t] * ct[m];
    m += f; if (m >= TT) m -= TT;
  }
  out[O_OFF + b * NE + f] = s / 255.f;
}

extern "C" void kernel_launch(void* const* d_in, const int* in_sizes, int n_in,
                              void* d_out, int out_size, void* d_ws, size_t ws_size,
                              hipStream_t stream) {
  (void)in_sizes; (void)n_in; (void)out_size; (void)ws_size;
  const float* s       = (const float*)d_in[0];
  const float* conv1_w = (const float*)d_in[1];
  const float* conv1_b = (const float*)d_in[2];
  const float* bn_g    = (const float*)d_in[3];
  const float* bn_b    = (const float*)d_in[4];
  const float* conv2_w = (const float*)d_in[5];
  const float* conv2_b = (const float*)d_in[6];
  const float* pw1     = (const float*)d_in[7];
  const float* pb1     = (const float*)d_in[8];
  const float* pw2     = (const float*)d_in[9];
  const float* pb2     = (const float*)d_in[10];
  float* out = (float*)d_out;
  char* ws   = (char*)d_ws;

  unsigned int* wp1u = (unsigned int*)(ws + WSB_WP1);
  unsigned int* wp2u = (unsigned int*)(ws + WSB_WP2);
  float* hf   = (float*)(ws + WSB_H);
  float* z    = (float*)(ws + WSB_Z);      // aliases wp1 (dead after conv1)
  float* bn   = (float*)(ws + WSB_BN);
  float* hmid = (float*)(ws + WSB_HMID);   // aliases hf (dead after conv2)

  bn_zero_k<<<1, 256, 0, stream>>>(bn);
  pack1_k<<<dim3(16, 8), 256, 0, stream>>>(conv1_w, wp1u);
  pack2_k<<<dim3(64, 8), 256, 0, stream>>>(conv2_w, wp2u);

  conv1_mfma<<<dim3(8, TB), 256, 0, stream>>>(s, wp1u, conv1_b, hf);
  bn_stats_k<<<TB, 256, 0, stream>>>(hf, bn);
  bn_final_k<<<1, 256, 0, stream>>>(bn_g, bn_b, bn);

  z_init_k<<<2040, 1024, 0, stream>>>(conv2_b, z);   // overwrites wp1 region
  conv2_mfma<<<dim3(8, TB), 256, 0, stream>>>(hf, wp2u, bn, z);

  mlp1_k<<<dim3(4, NE), 256, 0, stream>>>(z, pw1, pb1, hmid);
  mlp2_k<<<TB * NE / 4, 256, 0, stream>>>(hmid, pw2, pb2, out);
  amp_k<<<dim3(TB, 32), 256, 0, stream>>>(z, out);
  offset_k<<<TB, 128, 0, stream>>>(z, out);
}

// Round 5
// 1032.982 us; speedup vs baseline: 19.2780x; 1.0469x over previous
//
#include <hip/hip_runtime.h>
#include <math.h>

#define TB   64
#define TT   255
#define TIN  32
#define NH   256
#define NE   128
#define NK   255
#define NPAD 127

typedef __attribute__((ext_vector_type(8))) short short8;
typedef __attribute__((ext_vector_type(4))) float float4v;

// ---- workspace layout (byte offsets) ----
#define WSB_WP1  0u
#define WSB_Z    0u
#define WSB_WP2  8388608u
#define WSB_H    41811968u
#define WSB_HMID 41811968u
#define WSB_BN   58589184u   // 4 x 256 f32: sum1/sum2/sc/sh

// ---- output layout (float offsets) ----
#define O_AMP   0u
#define O_PHASE 8128u
#define O_FREQ  16320u
#define O_OFF   24448u

static __device__ __forceinline__ unsigned short f2bf(float f) {
  unsigned int u = __float_as_uint(f);
  unsigned int r = (u + 0x7FFFu + ((u >> 16) & 1u)) >> 16;
  return (unsigned short)r;
}
static __device__ __forceinline__ float bf2f(unsigned short s) {
  return __uint_as_float(((unsigned int)s) << 16);
}
static __device__ __forceinline__ short8 as_s8(uint4 v) {
  union { uint4 u; short8 s; } c; c.u = v; return c.s;
}

// ---------------- small init kernels ----------------
__global__ __launch_bounds__(256) void bn_zero_k(float* __restrict__ bn) {
  bn[threadIdx.x] = 0.f;
  bn[256 + threadIdx.x] = 0.f;
}

__global__ __launch_bounds__(1024) void z_init_k(const float* __restrict__ b2,
                                                 float* __restrict__ z) {
  int idx = blockIdx.x * 1024 + threadIdx.x;   // 2040*1024 == 64*128*255
  int e = (idx / TT) % NE;
  z[idx] = b2[e];
}

// ---------------- weight packing (hi/lo split) ----------------
// wp1[kk][et(16)][p(2)][lane][j]: split_p( w1[e=et*16+(lane&15)][i=(lane>>4)*8+j][kk] )
__global__ __launch_bounds__(256) void pack1_k(const float* __restrict__ w1,
                                               unsigned int* __restrict__ wp1u) {
  __shared__ float tile[512][33];
  const int et = blockIdx.x, kc = blockIdx.y;
  const int kk0 = kc * 32, cnt = min(32, NK - kk0);
  const int tid = threadIdx.x;
  for (int idx = tid; idx < 512 * 32; idx += 256) {
    int row = idx >> 5, kl = idx & 31;
    if (kl < cnt) {
      int e_l = row >> 5, i_l = row & 31;
      tile[row][kl] = w1[(size_t)((et * 16 + e_l) * TIN + i_l) * NK + kk0 + kl];
    }
  }
  __syncthreads();
  const int lane = tid >> 2, jp = (tid & 3) * 2;
  const int row0 = (lane & 15) * 32 + (lane >> 4) * 8 + jp;
  for (int kl = 0; kl < cnt; ++kl) {
    float w0 = tile[row0][kl], w1v = tile[row0 + 1][kl];
    unsigned short h0 = f2bf(w0), h1 = f2bf(w1v);
    unsigned short l0 = f2bf(w0 - bf2f(h0)), l1 = f2bf(w1v - bf2f(h1));
    size_t base = (size_t)(kk0 + kl) * 8192 + et * 512 + tid;
    wp1u[base] = (unsigned int)h0 | ((unsigned int)h1 << 16);
    wp1u[base + 256] = (unsigned int)l0 | ((unsigned int)l1 << 16);
  }
}

// wp2[kk][hcg(8)][et(8)][p(2)][lane][j]: split_p( w2[e=et*16+(lane&15)][h=hcg*32+(lane>>4)*8+j][kk] )
__global__ __launch_bounds__(256) void pack2_k(const float* __restrict__ w2,
                                               unsigned int* __restrict__ wp2u) {
  __shared__ float tile[512][33];
  const int hcg = blockIdx.x >> 3, et = blockIdx.x & 7, kc = blockIdx.y;
  const int kk0 = kc * 32, cnt = min(32, NK - kk0);
  const int tid = threadIdx.x;
  for (int idx = tid; idx < 512 * 32; idx += 256) {
    int row = idx >> 5, kl = idx & 31;
    if (kl < cnt) {
      int e_l = row >> 5, h_l = row & 31;
      tile[row][kl] = w2[(size_t)((et * 16 + e_l) * NH + hcg * 32 + h_l) * NK + kk0 + kl];
    }
  }
  __syncthreads();
  const int lane = tid >> 2, jp = (tid & 3) * 2;
  const int row0 = (lane & 15) * 32 + (lane >> 4) * 8 + jp;
  for (int kl = 0; kl < cnt; ++kl) {
    float w0 = tile[row0][kl], w1v = tile[row0 + 1][kl];
    unsigned short h0 = f2bf(w0), h1 = f2bf(w1v);
    unsigned short l0 = f2bf(w0 - bf2f(h0)), l1 = f2bf(w1v - bf2f(h1));
    size_t base = (size_t)(kk0 + kl) * 32768 + hcg * 4096 + et * 512 + tid;
    wp2u[base] = (unsigned int)h0 | ((unsigned int)h1 << 16);
    wp2u[base + 256] = (unsigned int)l0 | ((unsigned int)l1 << 16);
  }
}

// ---------------- conv1 MFMA (split-bf16 3-term, register-streamed B) ---------
// grid (8 = 2 th x 4 chg, 64 b), 256 thr. Block: 128t x 64ch.
// Waves: 2tg x 2eg, each 64t x 32ch (mi=4, ni=2). LDS 48 KB, NO K-loop barriers.
#define C1_ROWS 384
__global__ __launch_bounds__(256, 2) void conv1_mfma(
    const float* __restrict__ s, const unsigned int* __restrict__ wp1u,
    const float* __restrict__ b1v, float* __restrict__ hf) {
  __shared__ __align__(16) unsigned short Alds[C1_ROWS * 64];   // 49152 B
  const int th = blockIdx.x & 1, chg = blockIdx.x >> 1, b = blockIdx.y;
  const int tid = threadIdx.x, lane = tid & 63, wv = tid >> 6;
  const int quad = lane >> 4, l15 = lane & 15;
  const int tg = wv & 1, eg = wv >> 1;
  unsigned int* Au = (unsigned int*)Alds;

  for (int idx = tid; idx < C1_ROWS * 16; idx += 256) {
    int r = idx >> 4, p = idx & 15;
    int t = th * 128 + r - NPAD;
    float v0 = 0.f, v1 = 0.f;
    if (t >= 0 && t < TT) {
      const float* sp = &s[(size_t)(b * TT + t) * TIN + p * 2];
      v0 = sp[0]; v1 = sp[1];
    }
    unsigned short h0 = f2bf(v0), h1 = f2bf(v1);
    unsigned short l0 = f2bf(v0 - bf2f(h0)), l1 = f2bf(v1 - bf2f(h1));
    int sw = r & 7;
    Au[r * 32 + ((((p >> 2) ^ sw) << 2) | (p & 3))] = (unsigned int)h0 | ((unsigned int)h1 << 16);
    Au[r * 32 + (((((p >> 2) + 4) ^ sw) << 2) | (p & 3))] = (unsigned int)l0 | ((unsigned int)l1 << 16);
  }

#define LOADB1(buf, KK) do {                                                      \
    const uint4* _b = (const uint4*)(wp1u + (size_t)(KK) * 8192u) +               \
                      (chg * 4 + eg * 2) * 128;                                   \
    buf[0] = _b[lane];          buf[1] = _b[64 + lane];                           \
    buf[2] = _b[128 + lane];    buf[3] = _b[192 + lane];                          \
  } while (0)

#define MSTEP1(KK, buf) do {                                                      \
    short8 bh0 = as_s8(buf[0]), bl0 = as_s8(buf[1]);                              \
    short8 bh1 = as_s8(buf[2]), bl1 = as_s8(buf[3]);                              \
    _Pragma("unroll")                                                             \
    for (int mi = 0; mi < 4; ++mi) {                                              \
      const int row = tg * 64 + mi * 16 + l15 + (KK);                             \
      const int sw = row & 7;                                                     \
      short8 ah = *(const short8*)&Alds[row * 64 + ((quad ^ sw) << 3)];           \
      short8 al = *(const short8*)&Alds[row * 64 + (((quad ^ 4) ^ sw) << 3)];     \
      acc[mi][0] = __builtin_amdgcn_mfma_f32_16x16x32_bf16(ah, bh0, acc[mi][0], 0, 0, 0); \
      acc[mi][0] = __builtin_amdgcn_mfma_f32_16x16x32_bf16(ah, bl0, acc[mi][0], 0, 0, 0); \
      acc[mi][0] = __builtin_amdgcn_mfma_f32_16x16x32_bf16(al, bh0, acc[mi][0], 0, 0, 0); \
      acc[mi][1] = __builtin_amdgcn_mfma_f32_16x16x32_bf16(ah, bh1, acc[mi][1], 0, 0, 0); \
      acc[mi][1] = __builtin_amdgcn_mfma_f32_16x16x32_bf16(ah, bl1, acc[mi][1], 0, 0, 0); \
      acc[mi][1] = __builtin_amdgcn_mfma_f32_16x16x32_bf16(al, bh1, acc[mi][1], 0, 0, 0); \
    }                                                                             \
  } while (0)

  uint4 b0[4], b1x[4];
  LOADB1(b0, 0);
  __syncthreads();

  float4v acc[4][2];
#pragma unroll
  for (int mi = 0; mi < 4; ++mi)
#pragma unroll
    for (int ni = 0; ni < 2; ++ni) acc[mi][ni] = (float4v)(0.f);

  for (int kp = 0; kp < 127; ++kp) {
    const int kk = kp * 2;
    LOADB1(b1x, kk + 1);
    MSTEP1(kk, b0);
    LOADB1(b0, kk + 2);
    MSTEP1(kk + 1, b1x);
  }
  MSTEP1(254, b0);

#pragma unroll
  for (int mi = 0; mi < 4; ++mi) {
#pragma unroll
    for (int ni = 0; ni < 2; ++ni) {
      int ch = chg * 64 + (eg * 2 + ni) * 16 + l15;
      float bias = b1v[ch];
#pragma unroll
      for (int r = 0; r < 4; ++r) {
        int t = th * 128 + tg * 64 + mi * 16 + quad * 4 + r;
        if (t < TT)
          hf[(size_t)(b * 256 + t) * NH + ch] = fmaxf(acc[mi][ni][r] + bias, 0.f);
      }
    }
  }
#undef LOADB1
#undef MSTEP1
}

// ---------------- BN stats from fp32 h ----------------
__global__ __launch_bounds__(256) void bn_stats_k(const float* __restrict__ hf,
                                                  float* __restrict__ bn) {
  const int b = blockIdx.x, h = threadIdx.x;
  float s1 = 0.f, s2 = 0.f;
  for (int t = 0; t < TT; ++t) {
    float v = hf[(size_t)(b * 256 + t) * NH + h];
    s1 += v; s2 += v * v;
  }
  atomicAdd(&bn[h], s1);
  atomicAdd(&bn[256 + h], s2);
}

__global__ __launch_bounds__(256) void bn_final_k(const float* __restrict__ gamma,
                                                  const float* __restrict__ beta,
                                                  float* __restrict__ bn) {
  const int h = threadIdx.x;
  const float inv = 1.0f / (TB * TT);
  float m = bn[h] * inv;
  float var = bn[256 + h] * inv - m * m;
  float sc = gamma[h] / sqrtf(var + 1e-5f);
  bn[512 + h] = sc;
  bn[768 + h] = beta[h] - m * sc;
}

// ---------------- conv2 MFMA (split-bf16 3-term, register-streamed B) ---------
// grid (8 = 2 th x 4 hs, 64 b), 256 thr. Block: 128t x 128e, 2 h-chunks of 32.
// Waves: 4 eg, each 128t x 32e (mi=8, ni=2). LDS 48 KB, NO K-loop barriers.
#define C2_ROWS 384
__global__ __launch_bounds__(256, 2) void conv2_mfma(
    const float* __restrict__ hf, const unsigned int* __restrict__ wp2u,
    const float* __restrict__ bn, float* __restrict__ z) {
  __shared__ __align__(16) unsigned short Alds[C2_ROWS * 64];   // 49152 B
  const int th = blockIdx.x & 1, hs = blockIdx.x >> 1, b = blockIdx.y;
  const int tid = threadIdx.x, lane = tid & 63, eg = tid >> 6;
  const int quad = lane >> 4, l15 = lane & 15;
  unsigned int* Au = (unsigned int*)Alds;

#define LOADB2(buf, KK, HG) do {                                                  \
    const uint4* _b = (const uint4*)(wp2u + (size_t)(KK) * 32768u +               \
                                     (size_t)(HG) * 4096u) + (eg * 2) * 128;      \
    buf[0] = _b[lane];          buf[1] = _b[64 + lane];                           \
    buf[2] = _b[128 + lane];    buf[3] = _b[192 + lane];                          \
  } while (0)

#define MSTEP2(KK, buf) do {                                                      \
    short8 bh0 = as_s8(buf[0]), bl0 = as_s8(buf[1]);                              \
    short8 bh1 = as_s8(buf[2]), bl1 = as_s8(buf[3]);                              \
    _Pragma("unroll")                                                             \
    for (int mi = 0; mi < 8; ++mi) {                                              \
      const int row = mi * 16 + l15 + (KK);                                       \
      const int sw = row & 7;                                                     \
      short8 ah = *(const short8*)&Alds[row * 64 + ((quad ^ sw) << 3)];           \
      short8 al = *(const short8*)&Alds[row * 64 + (((quad ^ 4) ^ sw) << 3)];     \
      acc[mi][0] = __builtin_amdgcn_mfma_f32_16x16x32_bf16(ah, bh0, acc[mi][0], 0, 0, 0); \
      acc[mi][0] = __builtin_amdgcn_mfma_f32_16x16x32_bf16(ah, bl0, acc[mi][0], 0, 0, 0); \
      acc[mi][0] = __builtin_amdgcn_mfma_f32_16x16x32_bf16(al, bh0, acc[mi][0], 0, 0, 0); \
      acc[mi][1] = __builtin_amdgcn_mfma_f32_16x16x32_bf16(ah, bh1, acc[mi][1], 0, 0, 0); \
      acc[mi][1] = __builtin_amdgcn_mfma_f32_16x16x32_bf16(ah, bl1, acc[mi][1], 0, 0, 0); \
      acc[mi][1] = __builtin_amdgcn_mfma_f32_16x16x32_bf16(al, bh1, acc[mi][1], 0, 0, 0); \
    }                                                                             \
  } while (0)

  float4v acc[8][2];
#pragma unroll
  for (int mi = 0; mi < 8; ++mi)
#pragma unroll
    for (int ni = 0; ni < 2; ++ni) acc[mi][ni] = (float4v)(0.f);

  uint4 b0[4], b1x[4];

  for (int hc = 0; hc < 2; ++hc) {
    const int hcg = hs * 2 + hc;
    __syncthreads();   // all reads of Alds from previous chunk done
    for (int idx = tid; idx < C2_ROWS * 16; idx += 256) {
      int r = idx >> 4, p = idx & 15;
      int t = th * 128 + r - NPAD;
      float v0 = 0.f, v1 = 0.f;
      int h0c = hcg * 32 + p * 2;
      if (t >= 0 && t < TT) {
        const float* hp = &hf[(size_t)(b * 256 + t) * NH + h0c];
        v0 = hp[0] * bn[512 + h0c] + bn[768 + h0c];
        v1 = hp[1] * bn[512 + h0c + 1] + bn[768 + h0c + 1];
      }
      unsigned short h0 = f2bf(v0), h1 = f2bf(v1);
      unsigned short l0 = f2bf(v0 - bf2f(h0)), l1 = f2bf(v1 - bf2f(h1));
      int sw = r & 7;
      Au[r * 32 + ((((p >> 2) ^ sw) << 2) | (p & 3))] = (unsigned int)h0 | ((unsigned int)h1 << 16);
      Au[r * 32 + (((((p >> 2) + 4) ^ sw) << 2) | (p & 3))] = (unsigned int)l0 | ((unsigned int)l1 << 16);
    }
    if (hc == 0) LOADB2(b0, 0, hcg);
    __syncthreads();

    for (int kp = 0; kp < 127; ++kp) {
      const int kk = kp * 2;
      LOADB2(b1x, kk + 1, hcg);
      MSTEP2(kk, b0);
      LOADB2(b0, kk + 2, hcg);
      MSTEP2(kk + 1, b1x);
    }
    MSTEP2(254, b0);
    if (hc == 0) LOADB2(b0, 0, hcg + 1);   // cross-chunk prefetch
  }

#pragma unroll
  for (int mi = 0; mi < 8; ++mi) {
#pragma unroll
    for (int ni = 0; ni < 2; ++ni) {
      int e = (eg * 2 + ni) * 16 + l15;
#pragma unroll
      for (int r = 0; r < 4; ++r) {
        int t = th * 128 + mi * 16 + quad * 4 + r;
        if (t < TT) atomicAdd(&z[(size_t)(b * NE + e) * TT + t], acc[mi][ni][r]);
      }
    }
  }
#undef LOADB2
#undef MSTEP2
}

// ---------------- MLP layer 1 (fp32) ----------------
__global__ __launch_bounds__(256) void mlp1_k(const float* __restrict__ z,
                                              const float* __restrict__ pw1,
                                              const float* __restrict__ pb1,
                                              float* __restrict__ hmid) {
  const int TC = 128;
  __shared__ float zl[TC * 68];
  __shared__ float pl[TC * 68];
  const int c = blockIdx.y, h0 = blockIdx.x * 64, tid = threadIdx.x;
  const int h4 = tid & 15, b4 = tid >> 4;
  float acc[4][4];
#pragma unroll
  for (int a = 0; a < 4; ++a)
#pragma unroll
    for (int bb = 0; bb < 4; ++bb) acc[a][bb] = 0.f;
  for (int t0 = 0; t0 < TT; t0 += TC) {
    const int tc = min(TC, TT - t0);
    __syncthreads();
    for (int idx = tid; idx < 64 * tc; idx += 256) {
      int r = idx / tc, t = idx - r * tc;
      zl[t * 68 + r] = z[(size_t)(r * NE + c) * TT + t0 + t];
      pl[t * 68 + r] = pw1[(size_t)(c * NH + h0 + r) * TT + t0 + t];
    }
    __syncthreads();
    for (int t = 0; t < tc; ++t) {
      float4 zv = *(const float4*)&zl[t * 68 + b4 * 4];
      float4 pv = *(const float4*)&pl[t * 68 + h4 * 4];
      float zz[4] = {zv.x, zv.y, zv.z, zv.w};
      float pp[4] = {pv.x, pv.y, pv.z, pv.w};
#pragma unroll
      for (int a = 0; a < 4; ++a)
#pragma unroll
        for (int bb = 0; bb < 4; ++bb) acc[a][bb] = fmaf(pp[a], zz[bb], acc[a][bb]);
    }
  }
#pragma unroll
  for (int a = 0; a < 4; ++a) {
    int hh = h0 + h4 * 4 + a;
    float bias = pb1[c * NH + hh];
#pragma unroll
    for (int bb = 0; bb < 4; ++bb) {
      int bidx = b4 * 4 + bb;
      float v = acc[a][bb] + bias;
      hmid[(size_t)(bidx * NE + c) * NH + hh] = fmaxf(v, 0.f);
    }
  }
}

// ---------------- MLP layer 2 + atan2 ----------------
__global__ __launch_bounds__(256) void mlp2_k(const float* __restrict__ hmid,
                                              const float* __restrict__ pw2,
                                              const float* __restrict__ pb2,
                                              float* __restrict__ out) {
  const int tid = threadIdx.x, lane = tid & 63, wv = tid >> 6;
  const int p = blockIdx.x * 4 + wv;
  const int b = p >> 7, c = p & 127;
  const float4 hv = *(const float4*)&hmid[(size_t)(b * NE + c) * NH + lane * 4];
  const float4 p0 = *(const float4*)&pw2[(size_t)(c * 2 + 0) * NH + lane * 4];
  const float4 p1 = *(const float4*)&pw2[(size_t)(c * 2 + 1) * NH + lane * 4];
  float s0 = hv.x * p0.x + hv.y * p0.y + hv.z * p0.z + hv.w * p0.w;
  float s1 = hv.x * p1.x + hv.y * p1.y + hv.z * p1.z + hv.w * p1.w;
#pragma unroll
  for (int off = 32; off; off >>= 1) {
    s0 += __shfl_down(s0, off);
    s1 += __shfl_down(s1, off);
  }
  if (lane == 0) {
    float a0 = s0 + pb2[c * 2 + 0];
    float a1 = s1 + pb2[c * 2 + 1];
    out[O_PHASE + b * NE + c] = atan2f(a1, a0);
  }
}

// ---------------- amplitude (Parseval) + constant frequency ----------------
__global__ __launch_bounds__(256) void amp_k(const float* __restrict__ z,
                                             float* __restrict__ out) {
  const int tid = threadIdx.x, lane = tid & 63, wv = tid >> 6;
  const int b = blockIdx.x, c = blockIdx.y * 4 + wv;
  const float* row = z + (size_t)(b * NE + c) * TT;
  float s1 = 0.f, s2 = 0.f;
  for (int idx = lane; idx < TT; idx += 64) {
    float v = row[idx];
    s1 += v; s2 += v * v;
  }
#pragma unroll
  for (int off = 32; off; off >>= 1) {
    s1 += __shfl_down(s1, off);
    s2 += __shfl_down(s2, off);
  }
  if (lane == 0 && c >= 1) {
    float P = 0.5f * (255.f * s2 + s1 * s1);
    out[O_AMP + b * 127 + (c - 1)] = 2.f * sqrtf(P) / 255.f;
    out[O_FREQ + b * 127 + (c - 1)] = (float)c / 255.f;
  }
}

// ---------------- offset: real rfft spectrum of channel 0 ----------------
__global__ __launch_bounds__(128) void offset_k(const float* __restrict__ z,
                                                float* __restrict__ out) {
  __shared__ float zr[TT];
  __shared__ float ct[TT];
  const int b = blockIdx.x, tid = threadIdx.x;
  for (int idx = tid; idx < TT; idx += 128) {
    zr[idx] = z[(size_t)(b * NE + 0) * TT + idx];
    ct[idx] = cosf(6.283185307179586f * (float)idx / 255.f);
  }
  __syncthreads();
  const int f = tid;
  float s = 0.f;
  int m = 0;
  for (int t = 0; t < TT; ++t) {
    s += zr[t] * ct[m];
    m += f; if (m >= TT) m -= TT;
  }
  out[O_OFF + b * NE + f] = s / 255.f;
}

extern "C" void kernel_launch(void* const* d_in, const int* in_sizes, int n_in,
                              void* d_out, int out_size, void* d_ws, size_t ws_size,
                              hipStream_t stream) {
  (void)in_sizes; (void)n_in; (void)out_size; (void)ws_size;
  const float* s       = (const float*)d_in[0];
  const float* conv1_w = (const float*)d_in[1];
  const float* conv1_b = (const float*)d_in[2];
  const float* bn_g    = (const float*)d_in[3];
  const float* bn_b    = (const float*)d_in[4];
  const float* conv2_w = (const float*)d_in[5];
  const float* conv2_b = (const float*)d_in[6];
  const float* pw1     = (const float*)d_in[7];
  const float* pb1     = (const float*)d_in[8];
  const float* pw2     = (const float*)d_in[9];
  const float* pb2     = (const float*)d_in[10];
  float* out = (float*)d_out;
  char* ws   = (char*)d_ws;

  unsigned int* wp1u = (unsigned int*)(ws + WSB_WP1);
  unsigned int* wp2u = (unsigned int*)(ws + WSB_WP2);
  float* hf   = (float*)(ws + WSB_H);
  float* z    = (float*)(ws + WSB_Z);      // aliases wp1 (dead after conv1)
  float* bn   = (float*)(ws + WSB_BN);
  float* hmid = (float*)(ws + WSB_HMID);   // aliases hf (dead after conv2)

  bn_zero_k<<<1, 256, 0, stream>>>(bn);
  pack1_k<<<dim3(16, 8), 256, 0, stream>>>(conv1_w, wp1u);
  pack2_k<<<dim3(64, 8), 256, 0, stream>>>(conv2_w, wp2u);

  conv1_mfma<<<dim3(8, TB), 256, 0, stream>>>(s, wp1u, conv1_b, hf);
  bn_stats_k<<<TB, 256, 0, stream>>>(hf, bn);
  bn_final_k<<<1, 256, 0, stream>>>(bn_g, bn_b, bn);

  z_init_k<<<2040, 1024, 0, stream>>>(conv2_b, z);   // overwrites wp1 region
  conv2_mfma<<<dim3(8, TB), 256, 0, stream>>>(hf, wp2u, bn, z);

  mlp1_k<<<dim3(4, NE), 256, 0, stream>>>(z, pw1, pb1, hmid);
  mlp2_k<<<TB * NE / 4, 256, 0, stream>>>(hmid, pw2, pb2, out);
  amp_k<<<dim3(TB, 32), 256, 0, stream>>>(z, out);
  offset_k<<<TB, 128, 0, stream>>>(z, out);
}